// Round 2
// baseline (1088.946 us; speedup 1.0000x reference)
//
#include <hip/hip_runtime.h>
#include <math.h>

#define NFEAT 128
#define INF   64
#define BN_RSQ 0.99999500003749937f

template <int K, int MT, int MFULL, int EPI, int ITERS>
__launch_bounds__(256)
__global__ void linear_kernel(const float* __restrict__ in, const float* __restrict__ W,
                              const float* __restrict__ bias, const float* __restrict__ g,
                              const float* __restrict__ be, float* __restrict__ out,
                              int n, int moff) {
    constexpr int RPI = 256 / MT;
    __shared__ float Wl[K * MT];
    __shared__ float xl[RPI * (K + 1)];
    for (int i = threadIdx.x; i < K * MT; i += 256)
        Wl[i] = W[(i / MT) * MFULL + moff + (i % MT)];
    const int j = threadIdx.x % MT;
    const int r = threadIdx.x / MT;
    const int row0 = blockIdx.x * (RPI * ITERS);
    for (int it = 0; it < ITERS; ++it) {
        const int base = row0 + it * RPI;
        __syncthreads();
        for (int i = threadIdx.x; i < RPI * K; i += 256) {
            int rr = i / K, kk = i - rr * K;
            int row = base + rr;
            xl[rr * (K + 1) + kk] = (row < n) ? in[(long)row * K + kk] : 0.f;
        }
        __syncthreads();
        float acc = 0.f;
#pragma unroll
        for (int k = 0; k < K; ++k) acc += xl[r * (K + 1) + k] * Wl[k * MT + j];
        const int row = base + r;
        if (row < n) {
            float v = acc;
            if (bias) v += bias[moff + j];
            if (EPI >= 1) v = fmaxf(v, 0.f);
            if (EPI == 2) v = v * (g[moff + j] * BN_RSQ) + be[moff + j];
            out[(long)row * MFULL + moff + j] = v;
        }
    }
}

template <int H, int C>
__global__ void gat_logits_kernel(const float* __restrict__ xh, const float* __restrict__ a_s,
                                  const float* __restrict__ a_d, float* __restrict__ als,
                                  float* __restrict__ ald, int n) {
    int idx = blockIdx.x * blockDim.x + threadIdx.x;
    if (idx >= n * H) return;
    int node = idx / H, h = idx - node * H;
    const float* xp = xh + (long)node * NFEAT + h * C;
    float ss = 0.f, sd = 0.f;
#pragma unroll
    for (int c = 0; c < C; ++c) {
        float v = xp[c];
        ss += v * a_s[h * C + c];
        sd += v * a_d[h * C + c];
    }
    als[idx] = ss;
    ald[idx] = sd;
}

__global__ void zero_int_kernel(int* __restrict__ p, int n) {
    int i = blockIdx.x * blockDim.x + threadIdx.x;
    if (i < n) p[i] = 0;
}

__global__ void hist_kernel(const int* __restrict__ ei, int E, int n, int* __restrict__ deg) {
    int e = blockIdx.x * blockDim.x + threadIdx.x;
    if (e >= E + n) return;
    int d = (e < E) ? ei[E + e] : (e - E);
    atomicAdd(&deg[d], 1);
}

__global__ void scanA_kernel(const int* __restrict__ deg, int n,
                             int* __restrict__ rowptr, int* __restrict__ bsum) {
    __shared__ int s[256];
    int t = threadIdx.x;
    int idx = blockIdx.x * 256 + t;
    s[t] = (idx < n) ? deg[idx] : 0;
    __syncthreads();
    for (int o = 1; o < 256; o <<= 1) {
        int x = (t >= o) ? s[t - o] : 0;
        __syncthreads();
        s[t] += x;
        __syncthreads();
    }
    if (idx < n) rowptr[idx + 1] = s[t];
    if (t == 255) bsum[blockIdx.x] = s[255];
}

__global__ void scanB_kernel(int* __restrict__ bsum, int nb) {
    __shared__ int s[256];
    int t = threadIdx.x;
    s[t] = (t < nb) ? bsum[t] : 0;
    __syncthreads();
    for (int o = 1; o < 256; o <<= 1) {
        int x = (t >= o) ? s[t - o] : 0;
        __syncthreads();
        s[t] += x;
        __syncthreads();
    }
    if (t < nb) bsum[t] = s[t];
}

__global__ void scanC_kernel(const int* __restrict__ deg, int n, int* __restrict__ rowptr,
                             const int* __restrict__ bsum, int* __restrict__ cursor) {
    int idx = blockIdx.x * 256 + threadIdx.x;
    if (idx >= n) return;
    int off = (blockIdx.x > 0) ? bsum[blockIdx.x - 1] : 0;
    int val = rowptr[idx + 1] + off;
    rowptr[idx + 1] = val;
    cursor[idx] = val - deg[idx];
    if (idx == 0) rowptr[0] = 0;
}

__global__ void scatter_kernel(const int* __restrict__ ei, int E, int n,
                               int* __restrict__ cursor, int* __restrict__ csr_src) {
    int e = blockIdx.x * blockDim.x + threadIdx.x;
    if (e >= E + n) return;
    int s, d;
    if (e < E) { s = ei[e]; d = ei[E + e]; } else { s = e - E; d = s; }
    int pos = atomicAdd(&cursor[d], 1);
    csr_src[pos] = s;
}

template <int H>
__launch_bounds__(256)
__global__ void gat_gather_kernel(const int* __restrict__ rowptr, const int* __restrict__ csr_src,
                                  const float* __restrict__ xh, const float* __restrict__ als,
                                  const float* __restrict__ ald, const float* __restrict__ bias,
                                  const float* __restrict__ g, const float* __restrict__ be,
                                  const float* __restrict__ post, float* __restrict__ hout, int n) {
    const int lane = threadIdx.x & 63;
    const int d = blockIdx.x * 4 + (threadIdx.x >> 6);
    if (d >= n) return;
    const int c0 = lane, c1 = lane + 64;
    const int h0 = (H == 4) ? (lane >> 5) : 0;
    const int h1 = (H == 4) ? (h0 + 2) : 0;
    const float ad0 = ald[d * H + h0];
    const float ad1 = ald[d * H + h1];
    const int rs = rowptr[d], re = rowptr[d + 1];
    float m0 = -INFINITY, m1 = -INFINITY;
    float den0 = 0.f, den1 = 0.f, acc0 = 0.f, acc1 = 0.f;
    for (int base = rs; base < re; base += 64) {
        int sv = 0;
        if (base + lane < re) sv = csr_src[base + lane];
        const int cnt = min(64, re - base);
        for (int t = 0; t < cnt; ++t) {
            const int s = __shfl(sv, t, 64);
            float l0 = als[s * H + h0] + ad0;
            float l1 = als[s * H + h1] + ad1;
            l0 = l0 > 0.f ? l0 : 0.2f * l0;
            l1 = l1 > 0.f ? l1 : 0.2f * l1;
            const float x0 = xh[(long)s * NFEAT + c0];
            const float x1 = xh[(long)s * NFEAT + c1];
            const float nm0 = fmaxf(m0, l0), nm1 = fmaxf(m1, l1);
            const float sc0 = expf(m0 - nm0), sc1 = expf(m1 - nm1);
            const float w0 = expf(l0 - nm0), w1 = expf(l1 - nm1);
            den0 = den0 * sc0 + w0;       den1 = den1 * sc1 + w1;
            acc0 = acc0 * sc0 + w0 * x0;  acc1 = acc1 * sc1 + w1 * x1;
            m0 = nm0; m1 = nm1;
        }
    }
    float v0 = (acc0 / den0 + bias[c0]) * (g[c0] * BN_RSQ) + be[c0];
    float v1 = (acc1 / den1 + bias[c1]) * (g[c1] * BN_RSQ) + be[c1];
    v0 = v0 > 0.f ? v0 : expm1f(v0);
    v1 = v1 > 0.f ? v1 : expm1f(v1);
    if (post) { v0 *= post[c0]; v1 *= post[c1]; }
    hout[(long)d * NFEAT + c0] = v0;
    hout[(long)d * NFEAT + c1] = v1;
}

template <int H>
static void run_gat_layer(const float* hin, float* xh, float* als, float* ald,
                          const int* rowptr, const int* csr_src, int n,
                          const float* W, const float* as_, const float* ad_, const float* b,
                          const float* g, const float* be, const float* post, float* hout,
                          hipStream_t stream) {
    constexpr int C = NFEAT / H;
    const int gl = (n + 31) / 32;
    linear_kernel<128, 64, 128, 0, 8><<<gl, 256, 0, stream>>>(hin, W, nullptr, nullptr, nullptr, xh, n, 0);
    linear_kernel<128, 64, 128, 0, 8><<<gl, 256, 0, stream>>>(hin, W, nullptr, nullptr, nullptr, xh, n, 64);
    gat_logits_kernel<H, C><<<(n * H + 255) / 256, 256, 0, stream>>>(xh, as_, ad_, als, ald, n);
    gat_gather_kernel<H><<<(n + 3) / 4, 256, 0, stream>>>(rowptr, csr_src, xh, als, ald,
                                                          b, g, be, post, hout, n);
}

extern "C" void kernel_launch(void* const* d_in, const int* in_sizes, int n_in,
                              void* d_out, int out_size, void* d_ws, size_t ws_size,
                              hipStream_t stream) {
    const float* x   = (const float*)d_in[0];
    const int*   ei  = (const int*)d_in[1];
    const float* Wp  = (const float*)d_in[2];
    const float* bp  = (const float*)d_in[3];
    const float* W0  = (const float*)d_in[4];
    const float* as0 = (const float*)d_in[5];
    const float* ad0 = (const float*)d_in[6];
    const float* b0  = (const float*)d_in[7];
    const float* g0  = (const float*)d_in[8];
    const float* be0 = (const float*)d_in[9];
    const float* W1  = (const float*)d_in[10];
    const float* as1 = (const float*)d_in[11];
    const float* ad1 = (const float*)d_in[12];
    const float* b1  = (const float*)d_in[13];
    const float* g1  = (const float*)d_in[14];
    const float* be1 = (const float*)d_in[15];
    const float* W2  = (const float*)d_in[16];
    const float* as2 = (const float*)d_in[17];
    const float* ad2 = (const float*)d_in[18];
    const float* b2  = (const float*)d_in[19];
    const float* g2  = (const float*)d_in[20];
    const float* be2 = (const float*)d_in[21];
    const float* fi  = (const float*)d_in[22];
    const float* Wc1 = (const float*)d_in[23];
    const float* bc1 = (const float*)d_in[24];
    const float* gc  = (const float*)d_in[25];
    const float* bec = (const float*)d_in[26];
    const float* Wc2 = (const float*)d_in[27];
    const float* bc2 = (const float*)d_in[28];
    const float* Wc3 = (const float*)d_in[29];
    const float* bc3 = (const float*)d_in[30];

    const int n  = in_sizes[0] / INF;      // 50000
    const int E  = in_sizes[1] / 2;        // 800000
    const int E2 = E + n;                  // + self-loops
    const int NB = (n + 255) / 256;        // scan blocks (<=256)

    float* ws   = (float*)d_ws;
    float* h    = ws;                          // n*128
    float* xh   = h + (long)n * NFEAT;         // n*128
    float* als  = xh + (long)n * NFEAT;        // n*4
    float* ald  = als + (long)n * 4;           // n*4
    int* deg     = (int*)(ald + (long)n * 4);  // n
    int* rowptr  = deg + n;                    // n+1
    int* cursor  = rowptr + (n + 1);           // n
    int* csr_src = cursor + n;                 // E2
    int* bsum    = csr_src + (long)E2;         // NB

    // CSR build (by dst)
    zero_int_kernel<<<NB, 256, 0, stream>>>(deg, n);
    hist_kernel<<<(E2 + 255) / 256, 256, 0, stream>>>(ei, E, n, deg);
    scanA_kernel<<<NB, 256, 0, stream>>>(deg, n, rowptr, bsum);
    scanB_kernel<<<1, 256, 0, stream>>>(bsum, NB);
    scanC_kernel<<<NB, 256, 0, stream>>>(deg, n, rowptr, bsum, cursor);
    scatter_kernel<<<(E2 + 255) / 256, 256, 0, stream>>>(ei, E, n, cursor, csr_src);

    // projection: h = x @ Wp + bp
    linear_kernel<64, 128, 128, 0, 8><<<(n + 15) / 16, 256, 0, stream>>>(
        x, Wp, bp, nullptr, nullptr, h, n, 0);

    // GAT layers (h -> h in place across kernels)
    run_gat_layer<4>(h, xh, als, ald, rowptr, csr_src, n, W0, as0, ad0, b0, g0, be0, nullptr, h, stream);
    run_gat_layer<4>(h, xh, als, ald, rowptr, csr_src, n, W1, as1, ad1, b1, g1, be1, nullptr, h, stream);
    run_gat_layer<1>(h, xh, als, ald, rowptr, csr_src, n, W2, as2, ad2, b2, g2, be2, fi, h, stream);

    // classifier: c1 = bn(relu(h@Wc1+bc1)) -> xh ; c2 = relu(c1@Wc2+bc2) -> h ; out = c2@Wc3+bc3
    linear_kernel<128, 64, 64, 2, 8><<<(n + 31) / 32, 256, 0, stream>>>(
        h, Wc1, bc1, gc, bec, xh, n, 0);
    linear_kernel<64, 32, 32, 1, 8><<<(n + 63) / 64, 256, 0, stream>>>(
        xh, Wc2, bc2, nullptr, nullptr, h, n, 0);
    linear_kernel<32, 2, 2, 0, 2><<<(n + 255) / 256, 256, 0, stream>>>(
        h, Wc3, bc3, nullptr, nullptr, (float*)d_out, n, 0);
}

// Round 4
// 645.240 us; speedup vs baseline: 1.6877x; 1.6877x over previous
//
#include <hip/hip_runtime.h>
#include <math.h>

#define NFEAT 128
#define INF   64
#define BN_RSQ 0.99999500003749937f

// ---------------------------------------------------------------------------
// Register-tiled linear: out[n,NT] = epi(in[n,K] @ W[K,NT] + bias)
// 64x64 output tile/block, 16x16 threads, 4x4 micro-tile/thread.
// K staged in 64-chunks: xs[64r][68] (padded, float4-aligned), ws[64k][68].
// EPI: 0 = none, 2 = relu then BN(g,be)
// ---------------------------------------------------------------------------
template <int K, int NT, int EPI>
__launch_bounds__(256)
__global__ void linear4_kernel(const float* __restrict__ in, const float* __restrict__ W,
                               const float* __restrict__ bias, const float* __restrict__ g,
                               const float* __restrict__ be, float* __restrict__ out, int n) {
    __shared__ float xs[64 * 68];
    __shared__ float wsm[64 * 68];
    const int tx = threadIdx.x & 15;          // col group (4 cols)
    const int ty = threadIdx.x >> 4;          // row group (4 rows)
    const int row0 = blockIdx.x * 64;
    const int col0 = blockIdx.y * 64;
    float acc[4][4] = {};
    for (int kc = 0; kc < K; kc += 64) {
        __syncthreads();                      // previous chunk fully consumed
        // stage x chunk: 64 rows x 64 ks (float4 per thread x4)
        for (int i = threadIdx.x; i < 1024; i += 256) {
            const int rr = i >> 4;
            const int k4 = (i & 15) << 2;
            const int row = row0 + rr;
            float4 v = make_float4(0.f, 0.f, 0.f, 0.f);
            if (row < n) v = *(const float4*)&in[(long)row * K + kc + k4];
            *(float4*)&xs[rr * 68 + k4] = v;  // 68*4 = 272 B stride, 16B-aligned
        }
        // stage W chunk: 64 ks x 64 cols
        for (int i = threadIdx.x; i < 1024; i += 256) {
            const int kk = i >> 4;
            const int j4 = (i & 15) << 2;
            *(float4*)&wsm[kk * 68 + j4] =
                *(const float4*)&W[(long)(kc + kk) * NT + col0 + j4];
        }
        __syncthreads();
#pragma unroll 16
        for (int k = 0; k < 64; ++k) {
            const float4 wv = *(const float4*)&wsm[k * 68 + (tx << 2)];
            const float x0 = xs[(ty * 4 + 0) * 68 + k];
            const float x1 = xs[(ty * 4 + 1) * 68 + k];
            const float x2 = xs[(ty * 4 + 2) * 68 + k];
            const float x3 = xs[(ty * 4 + 3) * 68 + k];
            acc[0][0] = fmaf(x0, wv.x, acc[0][0]); acc[0][1] = fmaf(x0, wv.y, acc[0][1]);
            acc[0][2] = fmaf(x0, wv.z, acc[0][2]); acc[0][3] = fmaf(x0, wv.w, acc[0][3]);
            acc[1][0] = fmaf(x1, wv.x, acc[1][0]); acc[1][1] = fmaf(x1, wv.y, acc[1][1]);
            acc[1][2] = fmaf(x1, wv.z, acc[1][2]); acc[1][3] = fmaf(x1, wv.w, acc[1][3]);
            acc[2][0] = fmaf(x2, wv.x, acc[2][0]); acc[2][1] = fmaf(x2, wv.y, acc[2][1]);
            acc[2][2] = fmaf(x2, wv.z, acc[2][2]); acc[2][3] = fmaf(x2, wv.w, acc[2][3]);
            acc[3][0] = fmaf(x3, wv.x, acc[3][0]); acc[3][1] = fmaf(x3, wv.y, acc[3][1]);
            acc[3][2] = fmaf(x3, wv.z, acc[3][2]); acc[3][3] = fmaf(x3, wv.w, acc[3][3]);
        }
    }
    const int col = col0 + (tx << 2);
    float4 bv = make_float4(0.f, 0.f, 0.f, 0.f);
    if (bias) bv = *(const float4*)&bias[col];
    float4 gv, ev;
    if (EPI == 2) { gv = *(const float4*)&g[col]; ev = *(const float4*)&be[col]; }
#pragma unroll
    for (int i = 0; i < 4; ++i) {
        const int row = row0 + ty * 4 + i;
        if (row >= n) break;
        float4 v = make_float4(acc[i][0] + bv.x, acc[i][1] + bv.y,
                               acc[i][2] + bv.z, acc[i][3] + bv.w);
        if (EPI == 2) {
            v.x = fmaxf(v.x, 0.f) * (gv.x * BN_RSQ) + ev.x;
            v.y = fmaxf(v.y, 0.f) * (gv.y * BN_RSQ) + ev.y;
            v.z = fmaxf(v.z, 0.f) * (gv.z * BN_RSQ) + ev.z;
            v.w = fmaxf(v.w, 0.f) * (gv.w * BN_RSQ) + ev.w;
        }
        *(float4*)&out[(long)row * NT + col] = v;
    }
}

// ---------------------------------------------------------------------------
// Small linear (classifier tails): out[:,0:MT] = epi(in@W + b)
// ---------------------------------------------------------------------------
template <int K, int MT, int MFULL, int EPI, int ITERS>
__launch_bounds__(256)
__global__ void linear_kernel(const float* __restrict__ in, const float* __restrict__ W,
                              const float* __restrict__ bias, float* __restrict__ out, int n) {
    constexpr int RPI = 256 / MT;
    __shared__ float Wl[K * MT];
    __shared__ float xl[RPI * (K + 1)];
    for (int i = threadIdx.x; i < K * MT; i += 256)
        Wl[i] = W[(i / MT) * MFULL + (i % MT)];
    const int j = threadIdx.x % MT;
    const int r = threadIdx.x / MT;
    const int row0 = blockIdx.x * (RPI * ITERS);
    for (int it = 0; it < ITERS; ++it) {
        const int base = row0 + it * RPI;
        __syncthreads();
        for (int i = threadIdx.x; i < RPI * K; i += 256) {
            int rr = i / K, kk = i - rr * K;
            int row = base + rr;
            xl[rr * (K + 1) + kk] = (row < n) ? in[(long)row * K + kk] : 0.f;
        }
        __syncthreads();
        float acc = 0.f;
#pragma unroll
        for (int k = 0; k < K; ++k) acc += xl[r * (K + 1) + k] * Wl[k * MT + j];
        const int row = base + r;
        if (row < n) {
            float v = acc;
            if (bias) v += bias[j];
            if (EPI >= 1) v = fmaxf(v, 0.f);
            out[(long)row * MFULL + j] = v;
        }
    }
}

// ---------------------------------------------------------------------------
// Per-node attention logits (float4 inner loop)
// ---------------------------------------------------------------------------
template <int H, int C>
__global__ void gat_logits_kernel(const float* __restrict__ xh, const float* __restrict__ a_s,
                                  const float* __restrict__ a_d, float* __restrict__ als,
                                  float* __restrict__ ald, int n) {
    int idx = blockIdx.x * blockDim.x + threadIdx.x;
    if (idx >= n * H) return;
    int node = idx / H, h = idx - node * H;
    const float4* xp  = (const float4*)(xh + (long)node * NFEAT + h * C);
    const float4* asp = (const float4*)(a_s + h * C);
    const float4* adp = (const float4*)(a_d + h * C);
    float ss = 0.f, sd = 0.f;
#pragma unroll
    for (int c = 0; c < C / 4; ++c) {
        float4 v = xp[c], a = asp[c], b = adp[c];
        ss += v.x * a.x + v.y * a.y + v.z * a.z + v.w * a.w;
        sd += v.x * b.x + v.y * b.y + v.z * b.z + v.w * b.w;
    }
    als[idx] = ss;
    ald[idx] = sd;
}

// ---------------------------------------------------------------------------
// CSR build
// ---------------------------------------------------------------------------
__global__ void zero_int_kernel(int* __restrict__ p, int n) {
    int i = blockIdx.x * blockDim.x + threadIdx.x;
    if (i < n) p[i] = 0;
}

__global__ void hist_kernel(const int* __restrict__ ei, int E, int n, int* __restrict__ deg) {
    int e = blockIdx.x * blockDim.x + threadIdx.x;
    if (e >= E + n) return;
    int d = (e < E) ? ei[E + e] : (e - E);
    atomicAdd(&deg[d], 1);
}

__global__ void scanA_kernel(const int* __restrict__ deg, int n,
                             int* __restrict__ rowptr, int* __restrict__ bsum) {
    __shared__ int s[256];
    int t = threadIdx.x;
    int idx = blockIdx.x * 256 + t;
    s[t] = (idx < n) ? deg[idx] : 0;
    __syncthreads();
    for (int o = 1; o < 256; o <<= 1) {
        int x = (t >= o) ? s[t - o] : 0;
        __syncthreads();
        s[t] += x;
        __syncthreads();
    }
    if (idx < n) rowptr[idx + 1] = s[t];
    if (t == 255) bsum[blockIdx.x] = s[255];
}

__global__ void scanB_kernel(int* __restrict__ bsum, int nb) {
    __shared__ int s[256];
    int t = threadIdx.x;
    s[t] = (t < nb) ? bsum[t] : 0;
    __syncthreads();
    for (int o = 1; o < 256; o <<= 1) {
        int x = (t >= o) ? s[t - o] : 0;
        __syncthreads();
        s[t] += x;
        __syncthreads();
    }
    if (t < nb) bsum[t] = s[t];
}

__global__ void scanC_kernel(const int* __restrict__ deg, int n, int* __restrict__ rowptr,
                             const int* __restrict__ bsum, int* __restrict__ cursor) {
    int idx = blockIdx.x * 256 + threadIdx.x;
    if (idx >= n) return;
    int off = (blockIdx.x > 0) ? bsum[blockIdx.x - 1] : 0;
    int val = rowptr[idx + 1] + off;
    rowptr[idx + 1] = val;
    cursor[idx] = val - deg[idx];
    if (idx == 0) rowptr[0] = 0;
}

__global__ void scatter_kernel(const int* __restrict__ ei, int E, int n,
                               int* __restrict__ cursor, int* __restrict__ csr_src) {
    int e = blockIdx.x * blockDim.x + threadIdx.x;
    if (e >= E + n) return;
    int s, d;
    if (e < E) { s = ei[e]; d = ei[E + e]; } else { s = e - E; d = s; }
    int pos = atomicAdd(&cursor[d], 1);
    csr_src[pos] = s;
}

// ---------------------------------------------------------------------------
// Fused gather: softmax WITHOUT max-subtraction (logits bounded, exp-safe;
// the max cancels exactly in the softmax ratio), native __expf,
// 1-deep software-pipelined prefetch. One wave per dst node.
// ---------------------------------------------------------------------------
template <int H>
__launch_bounds__(256)
__global__ void gat_gather_kernel(const int* __restrict__ rowptr, const int* __restrict__ csr_src,
                                  const float* __restrict__ xh, const float* __restrict__ als,
                                  const float* __restrict__ ald, const float* __restrict__ bias,
                                  const float* __restrict__ g, const float* __restrict__ be,
                                  const float* __restrict__ post, float* __restrict__ hout, int n) {
    const int lane = threadIdx.x & 63;
    const int d = blockIdx.x * 4 + (threadIdx.x >> 6);
    if (d >= n) return;
    const int c0 = lane, c1 = lane + 64;
    const int h0 = (H == 4) ? (lane >> 5) : 0;
    const int h1 = (H == 4) ? (h0 + 2) : 0;
    const float ad0 = ald[d * H + h0];
    const float ad1 = ald[d * H + h1];
    const int rs = rowptr[d], re = rowptr[d + 1];   // deg >= 1 (self-loop)
    float den0 = 0.f, den1 = 0.f, acc0 = 0.f, acc1 = 0.f;
    for (int base = rs; base < re; base += 64) {
        int sv = 0;
        if (base + lane < re) sv = csr_src[base + lane];
        const int cnt = min(64, re - base);
        // prime the pipeline
        int s = __shfl(sv, 0, 64);
        float a0 = als[s * H + h0];
        float a1 = als[s * H + h1];
        float x0 = xh[(long)s * NFEAT + c0];
        float x1 = xh[(long)s * NFEAT + c1];
        for (int t = 0; t < cnt; ++t) {
            const float ca0 = a0, ca1 = a1, cx0 = x0, cx1 = x1;
            if (t + 1 < cnt) {                       // wave-uniform prefetch
                const int sn = __shfl(sv, t + 1, 64);
                a0 = als[sn * H + h0];
                a1 = als[sn * H + h1];
                x0 = xh[(long)sn * NFEAT + c0];
                x1 = xh[(long)sn * NFEAT + c1];
            }
            float l0 = ca0 + ad0, l1 = ca1 + ad1;
            l0 = l0 > 0.f ? l0 : 0.2f * l0;          // leaky_relu 0.2
            l1 = l1 > 0.f ? l1 : 0.2f * l1;
            const float w0 = __expf(l0), w1 = __expf(l1);
            den0 += w0;                den1 += w1;
            acc0 = fmaf(w0, cx0, acc0); acc1 = fmaf(w1, cx1, acc1);
        }
    }
    float v0 = (acc0 / den0 + bias[c0]) * (g[c0] * BN_RSQ) + be[c0];
    float v1 = (acc1 / den1 + bias[c1]) * (g[c1] * BN_RSQ) + be[c1];
    v0 = v0 > 0.f ? v0 : expm1f(v0);                 // elu
    v1 = v1 > 0.f ? v1 : expm1f(v1);
    if (post) { v0 *= post[c0]; v1 *= post[c1]; }
    hout[(long)d * NFEAT + c0] = v0;
    hout[(long)d * NFEAT + c1] = v1;
}

// ---------------------------------------------------------------------------
template <int H>
static void run_gat_layer(const float* hin, float* xh, float* als, float* ald,
                          const int* rowptr, const int* csr_src, int n,
                          const float* W, const float* as_, const float* ad_, const float* b,
                          const float* g, const float* be, const float* post, float* hout,
                          hipStream_t stream) {
    constexpr int C = NFEAT / H;
    dim3 grid((n + 63) / 64, 2);
    linear4_kernel<128, 128, 0><<<grid, 256, 0, stream>>>(hin, W, nullptr, nullptr, nullptr, xh, n);
    gat_logits_kernel<H, C><<<(n * H + 255) / 256, 256, 0, stream>>>(xh, as_, ad_, als, ald, n);
    gat_gather_kernel<H><<<(n + 3) / 4, 256, 0, stream>>>(rowptr, csr_src, xh, als, ald,
                                                          b, g, be, post, hout, n);
}

extern "C" void kernel_launch(void* const* d_in, const int* in_sizes, int n_in,
                              void* d_out, int out_size, void* d_ws, size_t ws_size,
                              hipStream_t stream) {
    const float* x   = (const float*)d_in[0];
    const int*   ei  = (const int*)d_in[1];
    const float* Wp  = (const float*)d_in[2];
    const float* bp  = (const float*)d_in[3];
    const float* W0  = (const float*)d_in[4];
    const float* as0 = (const float*)d_in[5];
    const float* ad0 = (const float*)d_in[6];
    const float* b0  = (const float*)d_in[7];
    const float* g0  = (const float*)d_in[8];
    const float* be0 = (const float*)d_in[9];
    const float* W1  = (const float*)d_in[10];
    const float* as1 = (const float*)d_in[11];
    const float* ad1 = (const float*)d_in[12];
    const float* b1  = (const float*)d_in[13];
    const float* g1  = (const float*)d_in[14];
    const float* be1 = (const float*)d_in[15];
    const float* W2  = (const float*)d_in[16];
    const float* as2 = (const float*)d_in[17];
    const float* ad2 = (const float*)d_in[18];
    const float* b2  = (const float*)d_in[19];
    const float* g2  = (const float*)d_in[20];
    const float* be2 = (const float*)d_in[21];
    const float* fi  = (const float*)d_in[22];
    const float* Wc1 = (const float*)d_in[23];
    const float* bc1 = (const float*)d_in[24];
    const float* gc  = (const float*)d_in[25];
    const float* bec = (const float*)d_in[26];
    const float* Wc2 = (const float*)d_in[27];
    const float* bc2 = (const float*)d_in[28];
    const float* Wc3 = (const float*)d_in[29];
    const float* bc3 = (const float*)d_in[30];

    const int n  = in_sizes[0] / INF;      // 50000
    const int E  = in_sizes[1] / 2;        // 800000
    const int E2 = E + n;                  // + self-loops
    const int NB = (n + 255) / 256;        // scan blocks (<=256)

    float* ws   = (float*)d_ws;
    float* h    = ws;                          // n*128
    float* xh   = h + (long)n * NFEAT;         // n*128
    float* als  = xh + (long)n * NFEAT;        // n*4
    float* ald  = als + (long)n * 4;           // n*4
    int* deg     = (int*)(ald + (long)n * 4);  // n
    int* rowptr  = deg + n;                    // n+1
    int* cursor  = rowptr + (n + 1);           // n
    int* csr_src = cursor + n;                 // E2
    int* bsum    = csr_src + (long)E2;         // NB

    // CSR build (by dst)
    zero_int_kernel<<<NB, 256, 0, stream>>>(deg, n);
    hist_kernel<<<(E2 + 255) / 256, 256, 0, stream>>>(ei, E, n, deg);
    scanA_kernel<<<NB, 256, 0, stream>>>(deg, n, rowptr, bsum);
    scanB_kernel<<<1, 256, 0, stream>>>(bsum, NB);
    scanC_kernel<<<NB, 256, 0, stream>>>(deg, n, rowptr, bsum, cursor);
    scatter_kernel<<<(E2 + 255) / 256, 256, 0, stream>>>(ei, E, n, cursor, csr_src);

    // projection: h = x @ Wp + bp
    {
        dim3 grid((n + 63) / 64, 2);
        linear4_kernel<64, 128, 0><<<grid, 256, 0, stream>>>(x, Wp, bp, nullptr, nullptr, h, n);
    }

    // GAT layers (h -> h across kernels; stream-ordered)
    run_gat_layer<4>(h, xh, als, ald, rowptr, csr_src, n, W0, as0, ad0, b0, g0, be0, nullptr, h, stream);
    run_gat_layer<4>(h, xh, als, ald, rowptr, csr_src, n, W1, as1, ad1, b1, g1, be1, nullptr, h, stream);
    run_gat_layer<1>(h, xh, als, ald, rowptr, csr_src, n, W2, as2, ad2, b2, g2, be2, fi, h, stream);

    // classifier: c1 = bn(relu(h@Wc1+bc1)) -> xh ; c2 = relu(c1@Wc2+bc2) -> h ; out
    {
        dim3 grid((n + 63) / 64, 1);
        linear4_kernel<128, 64, 2><<<grid, 256, 0, stream>>>(h, Wc1, bc1, gc, bec, xh, n);
    }
    linear_kernel<64, 32, 32, 1, 8><<<(n + 63) / 64, 256, 0, stream>>>(xh, Wc2, bc2, h, n);
    linear_kernel<32, 2, 2, 0, 2><<<(n + 255) / 256, 256, 0, stream>>>(h, Wc3, bc3, (float*)d_out, n);
}

// Round 5
// 633.092 us; speedup vs baseline: 1.7200x; 1.0192x over previous
//
#include <hip/hip_runtime.h>
#include <math.h>

#define NFEAT 128
#define INF   64
#define BN_RSQ 0.99999500003749937f

// ---------------------------------------------------------------------------
// linear8: out[n,128] = in[n,K] @ W[K,128] (+bias). 128x128 block tile,
// 8x8 microtile per thread (rows/cols strided by 16 so all LDS reads are
// conflict-free ds_read_b128 with the 36-float padded stride), K-chunk 32.
// 1 LDS byte per FMA (vs 2 for the 4x4 version).
// ---------------------------------------------------------------------------
template <int K>
__launch_bounds__(256)
__global__ void linear8_kernel(const float* __restrict__ in, const float* __restrict__ W,
                               const float* __restrict__ bias, float* __restrict__ out, int n) {
    __shared__ float xs[128 * 36];   // [row][k] padded: row stride 36 floats (144B)
    __shared__ float wt[128 * 36];   // [col][k] transposed, same padding
    const int tid = threadIdx.x;
    const int tx = tid & 15;         // col group
    const int ty = tid >> 4;         // row group (wave: ty 0..3 -> bank phases 0/4/8/12)
    const int row0 = blockIdx.x * 128;
    float acc[8][8] = {};
    for (int kc = 0; kc < K; kc += 32) {
        __syncthreads();
        // stage x: 128 rows x 32 ks; thread covers 4 float4 slots
#pragma unroll
        for (int r = 0; r < 4; ++r) {
            const int idx = tid + 256 * r;
            const int rr = idx >> 3;
            const int k4 = (idx & 7) << 2;
            const int row = row0 + rr;
            float4 v = make_float4(0.f, 0.f, 0.f, 0.f);
            if (row < n) v = *(const float4*)&in[(long)row * K + kc + k4];
            *(float4*)&xs[rr * 36 + k4] = v;
        }
        // stage W transposed: [col][k]
#pragma unroll
        for (int r = 0; r < 4; ++r) {
            const int idx = tid + 256 * r;
            const int kk = idx >> 5;
            const int c4 = (idx & 31) << 2;
            const float4 v = *(const float4*)&W[(long)(kc + kk) * 128 + c4];
            wt[(c4 + 0) * 36 + kk] = v.x;
            wt[(c4 + 1) * 36 + kk] = v.y;
            wt[(c4 + 2) * 36 + kk] = v.z;
            wt[(c4 + 3) * 36 + kk] = v.w;
        }
        __syncthreads();
#pragma unroll 2
        for (int k4 = 0; k4 < 32; k4 += 4) {
            float4 xa[8], wa[8];
#pragma unroll
            for (int i = 0; i < 8; ++i) xa[i] = *(const float4*)&xs[(ty + 16 * i) * 36 + k4];
#pragma unroll
            for (int j = 0; j < 8; ++j) wa[j] = *(const float4*)&wt[(tx + 16 * j) * 36 + k4];
#pragma unroll
            for (int i = 0; i < 8; ++i)
#pragma unroll
                for (int j = 0; j < 8; ++j) {
                    acc[i][j] = fmaf(xa[i].x, wa[j].x, acc[i][j]);
                    acc[i][j] = fmaf(xa[i].y, wa[j].y, acc[i][j]);
                    acc[i][j] = fmaf(xa[i].z, wa[j].z, acc[i][j]);
                    acc[i][j] = fmaf(xa[i].w, wa[j].w, acc[i][j]);
                }
        }
    }
#pragma unroll
    for (int i = 0; i < 8; ++i) {
        const int row = row0 + ty + 16 * i;
        if (row >= n) continue;
#pragma unroll
        for (int j = 0; j < 8; ++j) {
            const int col = tx + 16 * j;
            float v = acc[i][j];
            if (bias) v += bias[col];
            out[(long)row * 128 + col] = v;
        }
    }
}

// ---------------------------------------------------------------------------
// linear4 (kept for Wc1): 64x64 tile, 4x4 microtile. EPI 2 = relu then BN.
// ---------------------------------------------------------------------------
template <int K, int NT, int EPI>
__launch_bounds__(256)
__global__ void linear4_kernel(const float* __restrict__ in, const float* __restrict__ W,
                               const float* __restrict__ bias, const float* __restrict__ g,
                               const float* __restrict__ be, float* __restrict__ out, int n) {
    __shared__ float xs[64 * 68];
    __shared__ float wsm[64 * 68];
    const int tx = threadIdx.x & 15;
    const int ty = threadIdx.x >> 4;
    const int row0 = blockIdx.x * 64;
    const int col0 = blockIdx.y * 64;
    float acc[4][4] = {};
    for (int kc = 0; kc < K; kc += 64) {
        __syncthreads();
        for (int i = threadIdx.x; i < 1024; i += 256) {
            const int rr = i >> 4;
            const int k4 = (i & 15) << 2;
            const int row = row0 + rr;
            float4 v = make_float4(0.f, 0.f, 0.f, 0.f);
            if (row < n) v = *(const float4*)&in[(long)row * K + kc + k4];
            *(float4*)&xs[rr * 68 + k4] = v;
        }
        for (int i = threadIdx.x; i < 1024; i += 256) {
            const int kk = i >> 4;
            const int j4 = (i & 15) << 2;
            *(float4*)&wsm[kk * 68 + j4] =
                *(const float4*)&W[(long)(kc + kk) * NT + col0 + j4];
        }
        __syncthreads();
#pragma unroll 16
        for (int k = 0; k < 64; ++k) {
            const float4 wv = *(const float4*)&wsm[k * 68 + (tx << 2)];
            const float x0 = xs[(ty * 4 + 0) * 68 + k];
            const float x1 = xs[(ty * 4 + 1) * 68 + k];
            const float x2 = xs[(ty * 4 + 2) * 68 + k];
            const float x3 = xs[(ty * 4 + 3) * 68 + k];
            acc[0][0] = fmaf(x0, wv.x, acc[0][0]); acc[0][1] = fmaf(x0, wv.y, acc[0][1]);
            acc[0][2] = fmaf(x0, wv.z, acc[0][2]); acc[0][3] = fmaf(x0, wv.w, acc[0][3]);
            acc[1][0] = fmaf(x1, wv.x, acc[1][0]); acc[1][1] = fmaf(x1, wv.y, acc[1][1]);
            acc[1][2] = fmaf(x1, wv.z, acc[1][2]); acc[1][3] = fmaf(x1, wv.w, acc[1][3]);
            acc[2][0] = fmaf(x2, wv.x, acc[2][0]); acc[2][1] = fmaf(x2, wv.y, acc[2][1]);
            acc[2][2] = fmaf(x2, wv.z, acc[2][2]); acc[2][3] = fmaf(x2, wv.w, acc[2][3]);
            acc[3][0] = fmaf(x3, wv.x, acc[3][0]); acc[3][1] = fmaf(x3, wv.y, acc[3][1]);
            acc[3][2] = fmaf(x3, wv.z, acc[3][2]); acc[3][3] = fmaf(x3, wv.w, acc[3][3]);
        }
    }
    const int col = col0 + (tx << 2);
    float4 bv = make_float4(0.f, 0.f, 0.f, 0.f);
    if (bias) bv = *(const float4*)&bias[col];
    float4 gv, ev;
    if (EPI == 2) { gv = *(const float4*)&g[col]; ev = *(const float4*)&be[col]; }
#pragma unroll
    for (int i = 0; i < 4; ++i) {
        const int row = row0 + ty * 4 + i;
        if (row >= n) break;
        float4 v = make_float4(acc[i][0] + bv.x, acc[i][1] + bv.y,
                               acc[i][2] + bv.z, acc[i][3] + bv.w);
        if (EPI == 2) {
            v.x = fmaxf(v.x, 0.f) * (gv.x * BN_RSQ) + ev.x;
            v.y = fmaxf(v.y, 0.f) * (gv.y * BN_RSQ) + ev.y;
            v.z = fmaxf(v.z, 0.f) * (gv.z * BN_RSQ) + ev.z;
            v.w = fmaxf(v.w, 0.f) * (gv.w * BN_RSQ) + ev.w;
        }
        *(float4*)&out[(long)row * NT + col] = v;
    }
}

// ---------------------------------------------------------------------------
// Small linear (classifier tails)
// ---------------------------------------------------------------------------
template <int K, int MT, int MFULL, int EPI, int ITERS>
__launch_bounds__(256)
__global__ void linear_kernel(const float* __restrict__ in, const float* __restrict__ W,
                              const float* __restrict__ bias, float* __restrict__ out, int n) {
    constexpr int RPI = 256 / MT;
    __shared__ float Wl[K * MT];
    __shared__ float xl[RPI * (K + 1)];
    for (int i = threadIdx.x; i < K * MT; i += 256)
        Wl[i] = W[(i / MT) * MFULL + (i % MT)];
    const int j = threadIdx.x % MT;
    const int r = threadIdx.x / MT;
    const int row0 = blockIdx.x * (RPI * ITERS);
    for (int it = 0; it < ITERS; ++it) {
        const int base = row0 + it * RPI;
        __syncthreads();
        for (int i = threadIdx.x; i < RPI * K; i += 256) {
            int rr = i / K, kk = i - rr * K;
            int row = base + rr;
            xl[rr * (K + 1) + kk] = (row < n) ? in[(long)row * K + kk] : 0.f;
        }
        __syncthreads();
        float acc = 0.f;
#pragma unroll
        for (int k = 0; k < K; ++k) acc += xl[r * (K + 1) + k] * Wl[k * MT + j];
        const int row = base + r;
        if (row < n) {
            float v = acc;
            if (bias) v += bias[j];
            if (EPI >= 1) v = fmaxf(v, 0.f);
            out[(long)row * MFULL + j] = v;
        }
    }
}

// ---------------------------------------------------------------------------
// Per-node attention logits (float4 inner loop)
// ---------------------------------------------------------------------------
template <int H, int C>
__global__ void gat_logits_kernel(const float* __restrict__ xh, const float* __restrict__ a_s,
                                  const float* __restrict__ a_d, float* __restrict__ als,
                                  float* __restrict__ ald, int n) {
    int idx = blockIdx.x * blockDim.x + threadIdx.x;
    if (idx >= n * H) return;
    int node = idx / H, h = idx - node * H;
    const float4* xp  = (const float4*)(xh + (long)node * NFEAT + h * C);
    const float4* asp = (const float4*)(a_s + h * C);
    const float4* adp = (const float4*)(a_d + h * C);
    float ss = 0.f, sd = 0.f;
#pragma unroll
    for (int c = 0; c < C / 4; ++c) {
        float4 v = xp[c], a = asp[c], b = adp[c];
        ss += v.x * a.x + v.y * a.y + v.z * a.z + v.w * a.w;
        sd += v.x * b.x + v.y * b.y + v.z * b.z + v.w * b.w;
    }
    als[idx] = ss;
    ald[idx] = sd;
}

// ---------------------------------------------------------------------------
// CSR build
// ---------------------------------------------------------------------------
__global__ void zero_int_kernel(int* __restrict__ p, int n) {
    int i = blockIdx.x * blockDim.x + threadIdx.x;
    if (i < n) p[i] = 0;
}

__global__ void hist_kernel(const int* __restrict__ ei, int E, int n, int* __restrict__ deg) {
    int e = blockIdx.x * blockDim.x + threadIdx.x;
    if (e >= E + n) return;
    int d = (e < E) ? ei[E + e] : (e - E);
    atomicAdd(&deg[d], 1);
}

__global__ void scanA_kernel(const int* __restrict__ deg, int n,
                             int* __restrict__ rowptr, int* __restrict__ bsum) {
    __shared__ int s[256];
    int t = threadIdx.x;
    int idx = blockIdx.x * 256 + t;
    s[t] = (idx < n) ? deg[idx] : 0;
    __syncthreads();
    for (int o = 1; o < 256; o <<= 1) {
        int x = (t >= o) ? s[t - o] : 0;
        __syncthreads();
        s[t] += x;
        __syncthreads();
    }
    if (idx < n) rowptr[idx + 1] = s[t];
    if (t == 255) bsum[blockIdx.x] = s[255];
}

__global__ void scanB_kernel(int* __restrict__ bsum, int nb) {
    __shared__ int s[256];
    int t = threadIdx.x;
    s[t] = (t < nb) ? bsum[t] : 0;
    __syncthreads();
    for (int o = 1; o < 256; o <<= 1) {
        int x = (t >= o) ? s[t - o] : 0;
        __syncthreads();
        s[t] += x;
        __syncthreads();
    }
    if (t < nb) bsum[t] = s[t];
}

__global__ void scanC_kernel(const int* __restrict__ deg, int n, int* __restrict__ rowptr,
                             const int* __restrict__ bsum, int* __restrict__ cursor) {
    int idx = blockIdx.x * 256 + threadIdx.x;
    if (idx >= n) return;
    int off = (blockIdx.x > 0) ? bsum[blockIdx.x - 1] : 0;
    int val = rowptr[idx + 1] + off;
    rowptr[idx + 1] = val;
    cursor[idx] = val - deg[idx];
    if (idx == 0) rowptr[0] = 0;
}

__global__ void scatter_kernel(const int* __restrict__ ei, int E, int n,
                               int* __restrict__ cursor, int* __restrict__ csr_src) {
    int e = blockIdx.x * blockDim.x + threadIdx.x;
    if (e >= E + n) return;
    int s, d;
    if (e < E) { s = ei[e]; d = ei[E + e]; } else { s = e - E; d = s; }
    int pos = atomicAdd(&cursor[d], 1);
    csr_src[pos] = s;
}

// ---------------------------------------------------------------------------
// Fused gather v2: per 64-edge batch, each lane computes its OWN edge's
// per-head weights (1 float4 als load + H exps per lane per 64 edges),
// stashes (src, w[H]) in LDS; the t-loop is then 3 broadcast ds_read_b32
// + 2 xh loads + 2 FMA per edge (2 edges/iter for MLP). No max-subtraction
// (the max cancels exactly in the softmax ratio; logits are exp-safe).
// ---------------------------------------------------------------------------
template <int H>
__launch_bounds__(256)
__global__ void gat_gather_kernel(const int* __restrict__ rowptr, const int* __restrict__ csr_src,
                                  const float* __restrict__ xh, const float* __restrict__ als,
                                  const float* __restrict__ ald, const float* __restrict__ bias,
                                  const float* __restrict__ g, const float* __restrict__ be,
                                  const float* __restrict__ post, float* __restrict__ hout, int n) {
    __shared__ int   slds[4][64];
    __shared__ float wlds[4][64][H];
    const int lane = threadIdx.x & 63;
    const int wid  = threadIdx.x >> 6;
    const int d = blockIdx.x * 4 + wid;
    if (d >= n) return;
    const int c0 = lane, c1 = lane + 64;
    const int h0 = (H == 4) ? (lane >> 5) : 0;      // head of feature c0
    const int h1 = (H == 4) ? (h0 + 2) : 0;         // head of feature c1
    float4 adv;
    if (H == 4) adv = *(const float4*)&ald[d * 4];
    else        adv.x = ald[d];
    const int rs = rowptr[d], re = rowptr[d + 1];   // deg >= 1 (self-loop)
    float den0 = 0.f, den1 = 0.f, acc0 = 0.f, acc1 = 0.f;
    for (int base = rs; base < re; base += 64) {
        // ---- batch phase: lane's own edge -> weights into LDS ----
        const bool valid = (base + lane) < re;
        int sv = 0;
        if (valid) sv = csr_src[base + lane];
        if (H == 4) {
            const float4 a = *(const float4*)&als[sv * 4];
            float l0 = a.x + adv.x, l1 = a.y + adv.y, l2 = a.z + adv.z, l3 = a.w + adv.w;
            l0 = l0 > 0.f ? l0 : 0.2f * l0;
            l1 = l1 > 0.f ? l1 : 0.2f * l1;
            l2 = l2 > 0.f ? l2 : 0.2f * l2;
            l3 = l3 > 0.f ? l3 : 0.2f * l3;
            float4 wv;
            wv.x = valid ? __expf(l0) : 0.f;
            wv.y = valid ? __expf(l1) : 0.f;
            wv.z = valid ? __expf(l2) : 0.f;
            wv.w = valid ? __expf(l3) : 0.f;
            slds[wid][lane] = sv;
            *(float4*)&wlds[wid][lane][0] = wv;
        } else {
            float l = als[sv] + adv.x;
            l = l > 0.f ? l : 0.2f * l;
            slds[wid][lane] = sv;
            wlds[wid][lane][0] = valid ? __expf(l) : 0.f;
        }
        // DS pipe is in-order per wave; compiler inserts lgkmcnt before reads.
        const int cnt = min(64, re - base);
        const int cnt2 = (cnt + 1) & ~1;            // pad slots carry w=0
        for (int t = 0; t < cnt2; t += 2) {
            const int sa = slds[wid][t];
            const int sb = slds[wid][t + 1];
            float wa0, wa1, wb0, wb1;
            if (H == 4) {
                wa0 = wlds[wid][t][h0];     wa1 = wlds[wid][t][h1];
                wb0 = wlds[wid][t + 1][h0]; wb1 = wlds[wid][t + 1][h1];
            } else {
                wa0 = wlds[wid][t][0];      wa1 = wa0;
                wb0 = wlds[wid][t + 1][0];  wb1 = wb0;
            }
            const float xa0 = xh[(long)sa * NFEAT + c0];
            const float xa1 = xh[(long)sa * NFEAT + c1];
            const float xb0 = xh[(long)sb * NFEAT + c0];
            const float xb1 = xh[(long)sb * NFEAT + c1];
            den0 += wa0 + wb0;
            den1 += wa1 + wb1;
            acc0 = fmaf(wa0, xa0, acc0); acc0 = fmaf(wb0, xb0, acc0);
            acc1 = fmaf(wa1, xa1, acc1); acc1 = fmaf(wb1, xb1, acc1);
        }
    }
    float v0 = (acc0 / den0 + bias[c0]) * (g[c0] * BN_RSQ) + be[c0];
    float v1 = (acc1 / den1 + bias[c1]) * (g[c1] * BN_RSQ) + be[c1];
    v0 = v0 > 0.f ? v0 : expm1f(v0);                // elu
    v1 = v1 > 0.f ? v1 : expm1f(v1);
    if (post) { v0 *= post[c0]; v1 *= post[c1]; }
    hout[(long)d * NFEAT + c0] = v0;
    hout[(long)d * NFEAT + c1] = v1;
}

// ---------------------------------------------------------------------------
template <int H>
static void run_gat_layer(const float* hin, float* xh, float* als, float* ald,
                          const int* rowptr, const int* csr_src, int n,
                          const float* W, const float* as_, const float* ad_, const float* b,
                          const float* g, const float* be, const float* post, float* hout,
                          hipStream_t stream) {
    constexpr int C = NFEAT / H;
    linear8_kernel<128><<<(n + 127) / 128, 256, 0, stream>>>(hin, W, nullptr, xh, n);
    gat_logits_kernel<H, C><<<(n * H + 255) / 256, 256, 0, stream>>>(xh, as_, ad_, als, ald, n);
    gat_gather_kernel<H><<<(n + 3) / 4, 256, 0, stream>>>(rowptr, csr_src, xh, als, ald,
                                                          b, g, be, post, hout, n);
}

extern "C" void kernel_launch(void* const* d_in, const int* in_sizes, int n_in,
                              void* d_out, int out_size, void* d_ws, size_t ws_size,
                              hipStream_t stream) {
    const float* x   = (const float*)d_in[0];
    const int*   ei  = (const int*)d_in[1];
    const float* Wp  = (const float*)d_in[2];
    const float* bp  = (const float*)d_in[3];
    const float* W0  = (const float*)d_in[4];
    const float* as0 = (const float*)d_in[5];
    const float* ad0 = (const float*)d_in[6];
    const float* b0  = (const float*)d_in[7];
    const float* g0  = (const float*)d_in[8];
    const float* be0 = (const float*)d_in[9];
    const float* W1  = (const float*)d_in[10];
    const float* as1 = (const float*)d_in[11];
    const float* ad1 = (const float*)d_in[12];
    const float* b1  = (const float*)d_in[13];
    const float* g1  = (const float*)d_in[14];
    const float* be1 = (const float*)d_in[15];
    const float* W2  = (const float*)d_in[16];
    const float* as2 = (const float*)d_in[17];
    const float* ad2 = (const float*)d_in[18];
    const float* b2  = (const float*)d_in[19];
    const float* g2  = (const float*)d_in[20];
    const float* be2 = (const float*)d_in[21];
    const float* fi  = (const float*)d_in[22];
    const float* Wc1 = (const float*)d_in[23];
    const float* bc1 = (const float*)d_in[24];
    const float* gc  = (const float*)d_in[25];
    const float* bec = (const float*)d_in[26];
    const float* Wc2 = (const float*)d_in[27];
    const float* bc2 = (const float*)d_in[28];
    const float* Wc3 = (const float*)d_in[29];
    const float* bc3 = (const float*)d_in[30];

    const int n  = in_sizes[0] / INF;      // 50000
    const int E  = in_sizes[1] / 2;        // 800000
    const int E2 = E + n;                  // + self-loops
    const int NB = (n + 255) / 256;        // scan blocks (<=256)

    float* ws   = (float*)d_ws;
    float* h    = ws;                          // n*128
    float* xh   = h + (long)n * NFEAT;         // n*128
    float* als  = xh + (long)n * NFEAT;        // n*4
    float* ald  = als + (long)n * 4;           // n*4
    int* deg     = (int*)(ald + (long)n * 4);  // n
    int* rowptr  = deg + n;                    // n+1
    int* cursor  = rowptr + (n + 1);           // n
    int* csr_src = cursor + n;                 // E2
    int* bsum    = csr_src + (long)E2;         // NB

    // CSR build (by dst)
    zero_int_kernel<<<NB, 256, 0, stream>>>(deg, n);
    hist_kernel<<<(E2 + 255) / 256, 256, 0, stream>>>(ei, E, n, deg);
    scanA_kernel<<<NB, 256, 0, stream>>>(deg, n, rowptr, bsum);
    scanB_kernel<<<1, 256, 0, stream>>>(bsum, NB);
    scanC_kernel<<<NB, 256, 0, stream>>>(deg, n, rowptr, bsum, cursor);
    scatter_kernel<<<(E2 + 255) / 256, 256, 0, stream>>>(ei, E, n, cursor, csr_src);

    // projection: h = x @ Wp + bp
    linear8_kernel<64><<<(n + 127) / 128, 256, 0, stream>>>(x, Wp, bp, h, n);

    // GAT layers (h -> h across kernels; stream-ordered)
    run_gat_layer<4>(h, xh, als, ald, rowptr, csr_src, n, W0, as0, ad0, b0, g0, be0, nullptr, h, stream);
    run_gat_layer<4>(h, xh, als, ald, rowptr, csr_src, n, W1, as1, ad1, b1, g1, be1, nullptr, h, stream);
    run_gat_layer<1>(h, xh, als, ald, rowptr, csr_src, n, W2, as2, ad2, b2, g2, be2, fi, h, stream);

    // classifier: c1 = bn(relu(h@Wc1+bc1)) -> xh ; c2 = relu(c1@Wc2+bc2) -> h ; out
    {
        dim3 grid((n + 63) / 64, 1);
        linear4_kernel<128, 64, 2><<<grid, 256, 0, stream>>>(h, Wc1, bc1, gc, bec, xh, n);
    }
    linear_kernel<64, 32, 32, 1, 8><<<(n + 63) / 64, 256, 0, stream>>>(xh, Wc2, bc2, h, n);
    linear_kernel<32, 2, 2, 0, 2><<<(n + 255) / 256, 256, 0, stream>>>(h, Wc3, bc3, (float*)d_out, n);
}